// Round 11
// baseline (4883.361 us; speedup 1.0000x reference)
//
#include <hip/hip_runtime.h>
#include <hip/hip_cooperative_groups.h>

namespace cg = cooperative_groups;

#define BB 128
#define NPTS 20000
#define NSTEP 4
#define NITER 4
#define MT 1024

// ws float offsets (round-2 proven layout)
#define OFF_ANCHOR 0
#define OFF_G      384
#define OFF_AO     400
#define OFF_U      2448
#define OFF_XL     67984
#define OFF_H      166288
#define OFF_C      231824
#define OFF_GB     297360
#define OFF_RMN    428432
#define OFF_TM     461200
#define OFF_TV     493968

// d_out float offsets
#define OUT_VAR   7680
#define OUT_VIEWS 15360

__device__ __forceinline__ float sigf(float x){ return 1.0f/(1.0f+expf(-x)); }

__device__ __forceinline__ float blockSum256(float v, float* buf){
    for (int off = 32; off > 0; off >>= 1) v += __shfl_down(v, off, 64);
    int tid = threadIdx.x;
    __syncthreads();
    if ((tid & 63) == 0) buf[tid >> 6] = v;
    __syncthreads();
    return (buf[0] + buf[1]) + (buf[2] + buf[3]);
}

// same reduction tree, valid for blocks >256 threads: only waves 0-3 write partials
__device__ __forceinline__ float blockSum256g(float v, float* buf, int tid){
    for (int off = 32; off > 0; off >>= 1) v += __shfl_down(v, off, 64);
    __syncthreads();
    if (tid < 256 && (tid & 63) == 0) buf[tid >> 6] = v;
    __syncthreads();
    return (buf[0] + buf[1]) + (buf[2] + buf[3]);
}

__device__ __forceinline__ double blockSum256d(double v, double* buf){
    for (int off = 32; off > 0; off >>= 1) v += __shfl_down(v, off, 64);
    int tid = threadIdx.x;
    __syncthreads();
    if ((tid & 63) == 0) buf[tid >> 6] = v;
    __syncthreads();
    return (buf[0] + buf[1]) + (buf[2] + buf[3]);
}

// ---------------- init ----------------
__global__ __launch_bounds__(256) void k_init(const float* __restrict__ inp, float* __restrict__ ws)
{
    int i = blockIdx.x*256 + threadIdx.x;
    if (i < BB*3) ws[OFF_ANCHOR + i] = inp[i];
}

// Precompute per-step G (2x2) and Ao (256x2) with fp64 accumulation.
__global__ __launch_bounds__(256) void k_pre(const float* __restrict__ Wq, const float* __restrict__ Wk,
                                             const float* __restrict__ Wv, const float* __restrict__ Win,
                                             const float* __restrict__ Wout, float* __restrict__ ws)
{
    __shared__ float wql[512], wkl[512], wvl[512];
    __shared__ double avl[512];
    __shared__ double dbuf[4];
    int s = blockIdx.x, t = threadIdx.x;
    wql[t] = Wq[s*512 + t];   wql[256+t] = Wq[s*512 + 256 + t];
    wkl[t] = Wk[s*512 + t];   wkl[256+t] = Wk[s*512 + 256 + t];
    wvl[t] = Wv[s*512 + t];   wvl[256+t] = Wv[s*512 + 256 + t];
    __syncthreads();
    const float* wq = Win + s*196608 + t*256;
    const float* wk = wq + 65536;
    const float* wv = wq + 131072;
    double aq0=0,aq1=0,ak0=0,ak1=0,av0=0,av1=0;
    for (int j = 0; j < 256; j++){
        double a = wq[j], b = wk[j], c = wv[j];
        aq0 += a*(double)wql[j*2]; aq1 += a*(double)wql[j*2+1];
        ak0 += b*(double)wkl[j*2]; ak1 += b*(double)wkl[j*2+1];
        av0 += c*(double)wvl[j*2]; av1 += c*(double)wvl[j*2+1];
    }
    avl[t*2] = av0; avl[t*2+1] = av1;
    double g00 = blockSum256d(aq0*ak0, dbuf);
    double g01 = blockSum256d(aq0*ak1, dbuf);
    double g10 = blockSum256d(aq1*ak0, dbuf);
    double g11 = blockSum256d(aq1*ak1, dbuf);
    if (t == 0){
        ws[OFF_G + s*4+0] = (float)g00; ws[OFF_G + s*4+1] = (float)g01;
        ws[OFF_G + s*4+2] = (float)g10; ws[OFF_G + s*4+3] = (float)g11;
    }
    const float* wo = Wout + s*65536 + t*256;
    double o0 = 0.0, o1 = 0.0;
    for (int j = 0; j < 256; j++){
        double w = wo[j];
        o0 += w*avl[j*2]; o1 += w*avl[j*2+1];
    }
    ws[OFF_AO + s*512 + t*2]   = (float)o0;
    ws[OFF_AO + s*512 + t*2+1] = (float)o1;
}

// ---------------- fused: map top-256 + views + enc LN + attn -> U + step init (1024 thr) ----------------
__global__ __launch_bounds__(MT) void k_mapenc(const float* __restrict__ mp, float* __restrict__ ws,
                                               float* __restrict__ out, const float* __restrict__ Wenc,
                                               const float* __restrict__ endp, int s, int t, int wprev)
{
    __shared__ unsigned int histx[256], histy[256];
    __shared__ float vx[1024], vy[1024];
    __shared__ float candx[448], candy[448];
    __shared__ float mxS[256], myS[256];
    __shared__ int scanx[256], scany[256];
    __shared__ int shjx, shjy;
    __shared__ unsigned int cnt_in, cntx, cnty;
    __shared__ float rbuf[4];
    int tid = threadIdx.x, b = blockIdx.x;
    float ax = ws[OFF_ANCHOR + b*3 + 0];
    float ay = ws[OFF_ANCHOR + b*3 + 1];
    float th = ws[OFF_ANCHOR + b*3 + 2];
    float cth = cosf(th), sth = sinf(th);
    if (tid < 256){ histx[tid] = 0u; histy[tid] = 0u; }
    if (tid == 0){ cnt_in = 0u; cntx = 0u; cnty = 0u; }
    __syncthreads();
    for (int i = tid; i < NPTS; i += MT){
        float dx = mp[i] - ax, dy = mp[NPTS + i] - ay;
        float rx = cth*dx + sth*dy;
        float ry = cth*dy - sth*dx;
        float d  = sqrtf(rx*rx + ry*ry);
        if (d < 10.0f){
            unsigned p = atomicAdd(&cnt_in, 1u);
            if (p < 1024u){ vx[p] = rx; vy[p] = ry; }
            int bx = min(max((int)((rx + 10.0f)*12.8f), 0), 255);
            int by = min(max((int)((ry + 10.0f)*12.8f), 0), 255);
            atomicAdd(&histx[bx], 1u); atomicAdd(&histy[by], 1u);
        }
    }
    __syncthreads();
    int total = (int)min(cnt_in, 1024u);
    int K = min(256, total);
    int px = 0, py = 0;
    if (tid < 256){
        px = (int)histx[tid]; py = (int)histy[tid];
        scanx[tid] = px; scany[tid] = py;
    }
    __syncthreads();
    for (int off = 1; off < 256; off <<= 1){
        int vxs = 0, vys = 0;
        if (tid < 256){
            vxs = (tid >= off) ? scanx[tid - off] : 0;
            vys = (tid >= off) ? scany[tid - off] : 0;
        }
        __syncthreads();
        if (tid < 256){ scanx[tid] += vxs; scany[tid] += vys; }
        __syncthreads();
    }
    if (K > 0){
        if (tid < 256){
            if (scanx[tid] - px < K && scanx[tid] >= K) shjx = tid;
            if (scany[tid] - py < K && scany[tid] >= K) shjy = tid;
        }
    } else if (tid == 0){ shjx = -1; shjy = -1; }
    __syncthreads();
    int jx = shjx, jy = shjy;
    for (int i = tid; i < total; i += MT){
        float v = vx[i];
        int bx = min(max((int)((v + 10.0f)*12.8f), 0), 255);
        if (bx <= jx){ unsigned p = atomicAdd(&cntx, 1u); if (p < 448u) candx[p] = v; }
        v = vy[i];
        int by = min(max((int)((v + 10.0f)*12.8f), 0), 255);
        if (by <= jy){ unsigned p = atomicAdd(&cnty, 1u); if (p < 448u) candy[p] = v; }
    }
    __syncthreads();
    int cx = (int)min(cntx, 448u), cy = (int)min(cnty, 448u);
    // exact rank-select (ties by index; equal values interchange -> same output values)
    for (int i = tid; i < cx; i += MT){
        float v = candx[i];
        int r = 0;
        for (int j2 = 0; j2 < cx; j2++){
            float w2 = candx[j2];
            r += (w2 < v) || (w2 == v && j2 < i);
        }
        if (r < 256) mxS[r] = v;
    }
    for (int i = tid; i < cy; i += MT){
        float v = candy[i];
        int r = 0;
        for (int j2 = 0; j2 < cy; j2++){
            float w2 = candy[j2];
            r += (w2 < v) || (w2 == v && j2 < i);
        }
        if (r < 256) myS[r] = v;
    }
    __syncthreads();
    float mlx = 0.f, mly = 0.f;
    if (tid < 256){
        mlx = (tid < K) ? mxS[tid] : 0.0f;
        mly = (tid < K) ? myS[tid] : 0.0f;
        int obase = OUT_VIEWS + (((b*NSTEP + s)*5 + t)*2)*256;
        out[obase + tid]       = mlx;
        out[obase + 256 + tid] = mly;
        if (wprev){
            int pbase = OUT_VIEWS + (((b*NSTEP + (s-1))*5 + 4)*2)*256;
            out[pbase + tid]       = mlx;
            out[pbase + 256 + tid] = mly;
        }
    }
    if (t == 4) return;
    __syncthreads();
    if (tid < 256){ mxS[tid] = mlx; myS[tid] = mly; }   // zero-padded ml
    __syncthreads();
    // enc_a -> LN -> xl[0:256]
    float accv = 0.f, dd = 0.f;
    if (tid < 256){
        float a0 = ax, a1 = ay, a2 = th;
        float z9[9] = {a0, a1, a2, a0-endp[0], a1-endp[1], a2-endp[2], 0.01f, 0.01f, 0.01f};
        const float* w = Wenc + s*2304 + tid*9;
        #pragma unroll
        for (int j2 = 0; j2 < 9; j2++) accv += z9[j2]*w[j2];
    }
    float mu = blockSum256g(accv, rbuf, tid) * (1.0f/256.0f);
    dd = accv - mu;
    float var = blockSum256g(tid < 256 ? dd*dd : 0.f, rbuf, tid) * (1.0f/256.0f);
    if (tid < 256)
        ws[OFF_XL + b*512 + tid] = dd * rsqrtf(var + 1e-5f);
    // rank-2 attention -> u
    if (tid < 256){
        float g00 = ws[OFF_G + s*4+0], g01 = ws[OFF_G + s*4+1];
        float g10 = ws[OFF_G + s*4+2], g11 = ws[OFF_G + s*4+3];
        float xq = mxS[tid], yq = myS[tid];
        float t0 = g00*xq + g10*yq;
        float t1 = g01*xq + g11*yq;
        float mxv = -1e30f;
        for (int j2 = 0; j2 < 256; j2++){
            float l = (t0*mxS[j2] + t1*myS[j2]) * 0.0625f;
            mxv = fmaxf(mxv, l);
        }
        float sum = 0.f, ux = 0.f, uy = 0.f;
        for (int j2 = 0; j2 < 256; j2++){
            float l = (t0*mxS[j2] + t1*myS[j2]) * 0.0625f;
            float e = expf(l - mxv);
            sum += e; ux += e*mxS[j2]; uy += e*myS[j2];
        }
        float inv = 1.0f/sum;
        ws[OFF_U + b*512 + tid*2]   = ux*inv;
        ws[OFF_U + b*512 + tid*2+1] = uy*inv;
        if (t == 0){
            ws[OFF_H + b*256 + tid] = 1.0f;
            ws[OFF_H + BB*256 + b*256 + tid] = 1.0f;
            ws[OFF_C + b*256 + tid] = 1.0f;
            ws[OFF_C + BB*256 + b*256 + tid] = 1.0f;
            if (tid < 3){
                out[((b*NSTEP + s)*5 + 0)*3 + tid] = ws[OFF_ANCHOR + b*3 + tid];
                out[OUT_VAR + ((b*NSTEP + s)*5 + 0)*3 + tid] = 0.01f;
            }
        }
    }
}

// ---------------- k_big: round-10 verbatim (97us proven) -> GB partials ----------------
__global__ __launch_bounds__(256) void k_big(float* __restrict__ ws, const float* __restrict__ W1,
                                             const float* __restrict__ W2, int s)
{
    __shared__ __align__(16) float ul[512];
    __shared__ float aol[128];
    __shared__ float w2l[64];
    __shared__ __align__(16) float xt[64*36];
    __shared__ __align__(16) float w1t[64*36];
    __shared__ float red[64*17];
    int sct = blockIdx.x, st = blockIdx.y, b = blockIdx.z;
    int tid = threadIdx.x, tx = tid & 15, ty = tid >> 4;
    {
        float2 uv = *(const float2*)(ws + OFF_U + b*512 + tid*2);
        ul[tid*2] = uv.x; ul[tid*2+1] = uv.y;
        if (tid < 128) aol[tid] = ws[OFF_AO + s*512 + st*128 + tid];
        if (tid < 64)  w2l[tid] = W2[sct*64 + tid];
    }
    __syncthreads();
    float acc[4][4];
    #pragma unroll
    for (int i=0;i<4;i++){
        #pragma unroll
        for (int j=0;j<4;j++) acc[i][j] = 0.f;
    }
    for (int mt = 0; mt < 8; mt++){
        {
            int cl = tid >> 2, f0 = tid & 3;
            const float* g = W1 + (sct*64 + cl)*256 + mt*32 + f0*4;
            float4 v0 = *(const float4*)g;
            float4 v1 = *(const float4*)(g + 16);
            *(float4*)(w1t + cl*36 + f0*4)      = v0;
            *(float4*)(w1t + cl*36 + f0*4 + 16) = v1;
        }
        {
            int r = tid >> 2, mg = tid & 3;
            float A0 = aol[r*2], A1 = aol[r*2+1];
            int m0 = mt*32 + mg*4;
            float4 o0, o1;
            o0.x = fmaxf(A0*ul[(m0+0)*2] + A1*ul[(m0+0)*2+1], 0.f);
            o0.y = fmaxf(A0*ul[(m0+1)*2] + A1*ul[(m0+1)*2+1], 0.f);
            o0.z = fmaxf(A0*ul[(m0+2)*2] + A1*ul[(m0+2)*2+1], 0.f);
            o0.w = fmaxf(A0*ul[(m0+3)*2] + A1*ul[(m0+3)*2+1], 0.f);
            int m1 = mt*32 + (mg+4)*4;
            o1.x = fmaxf(A0*ul[(m1+0)*2] + A1*ul[(m1+0)*2+1], 0.f);
            o1.y = fmaxf(A0*ul[(m1+1)*2] + A1*ul[(m1+1)*2+1], 0.f);
            o1.z = fmaxf(A0*ul[(m1+2)*2] + A1*ul[(m1+2)*2+1], 0.f);
            o1.w = fmaxf(A0*ul[(m1+3)*2] + A1*ul[(m1+3)*2+1], 0.f);
            *(float4*)(xt + r*36 + mg*4)     = o0;
            *(float4*)(xt + r*36 + (mg+4)*4) = o1;
        }
        __syncthreads();
        #pragma unroll
        for (int m4 = 0; m4 < 8; m4++){
            float4 xv[4], wv[4];
            #pragma unroll
            for (int i=0;i<4;i++) xv[i] = *(const float4*)(xt + (ty + 16*i)*36 + m4*4);
            #pragma unroll
            for (int j=0;j<4;j++) wv[j] = *(const float4*)(w1t + (tx + 16*j)*36 + m4*4);
            #pragma unroll
            for (int i=0;i<4;i++){
                #pragma unroll
                for (int j=0;j<4;j++){
                    acc[i][j] += xv[i].x*wv[j].x + xv[i].y*wv[j].y + xv[i].z*wv[j].z + xv[i].w*wv[j].w;
                }
            }
        }
        __syncthreads();
    }
    #pragma unroll
    for (int i=0;i<4;i++){
        float p = 0.f;
        #pragma unroll
        for (int j=0;j<4;j++) p += fmaxf(acc[i][j], 0.f) * w2l[tx + 16*j];
        red[(ty + 16*i)*17 + tx] = p;
    }
    __syncthreads();
    if (tid < 64){
        float sm = 0.f;
        #pragma unroll
        for (int q=0;q<16;q++) sm += red[tid*17 + q];
        ws[OFF_GB + b*1024 + sct*256 + st*64 + tid] = sm;
    }
}

// ---------------- generic small GEMM pass (round-2 verbatim) ----------------
template<int K>
__device__ __forceinline__ void gemm_pass(const float* __restrict__ A, const float* __restrict__ W,
                                          float* As, float* Wsh, float (&acc)[2][4],
                                          int bt, int ot, int tid)
{
    int tx = tid & 15, ty = tid >> 4;
    for (int kt = 0; kt < K/32; kt++){
        {
            int bb = tid >> 3, kk = (tid & 7) * 4;
            float4 v = *(const float4*)(A + (bt*32+bb)*K + kt*32 + kk);
            float* ap = As + bb*33 + kk;
            ap[0]=v.x; ap[1]=v.y; ap[2]=v.z; ap[3]=v.w;
        }
        {
            int oo = tid >> 2, kk = (tid & 3) * 8;
            const float* g = W + (ot*64+oo)*K + kt*32 + kk;
            float4 v0 = *(const float4*)g;
            float4 v1 = *(const float4*)(g + 4);
            float* wp = Wsh + oo*33 + kk;
            wp[0]=v0.x; wp[1]=v0.y; wp[2]=v0.z; wp[3]=v0.w;
            wp[4]=v1.x; wp[5]=v1.y; wp[6]=v1.z; wp[7]=v1.w;
        }
        __syncthreads();
        #pragma unroll
        for (int kk = 0; kk < 32; kk++){
            float a0 = As[(ty*2)*33 + kk], a1 = As[(ty*2+1)*33 + kk];
            float w0 = Wsh[(tx*4)*33+kk],   w1 = Wsh[(tx*4+1)*33+kk];
            float w2 = Wsh[(tx*4+2)*33+kk], w3 = Wsh[(tx*4+3)*33+kk];
            acc[0][0] += a0*w0; acc[0][1] += a0*w1; acc[0][2] += a0*w2; acc[0][3] += a0*w3;
            acc[1][0] += a1*w0; acc[1][1] += a1*w1; acc[1][2] += a1*w2; acc[1][3] += a1*w3;
        }
        __syncthreads();
    }
}

// ---------------- cooperative tail: lnencm | gemm512 | gates0 | gemm256 | mn | heads2 | head ----------------
// 64 blocks x 256 threads; each phase reproduces the round-10 per-block kernel verbatim.
__global__ __launch_bounds__(256) void k_tail(
    const float* __restrict__ Wih0, const float* __restrict__ Whh0,
    const float* __restrict__ Wih1, const float* __restrict__ Whh1,
    const float* __restrict__ Wm1, const float* __restrict__ Wv1,
    const float* __restrict__ Wm2, const float* __restrict__ Wv2,
    const float* __restrict__ dlm, float* __restrict__ ws, float* __restrict__ out,
    int s, int t)
{
    cg::grid_group grid = cg::this_grid();
    __shared__ float As[32*33];
    __shared__ float Wsh[64*33];
    __shared__ float rbuf[4];
    int g = blockIdx.x, tid = threadIdx.x;
    int tx = tid & 15, ty = tid >> 4;

    // Phase A: lnencm (sum 4 partials sct-ascending -> LN -> xl[:,256:512]), b = 2g, 2g+1
    for (int bb = 0; bb < 2; bb++){
        int b = g*2 + bb;
        const float* p = ws + OFF_GB + b*1024;
        float v = p[tid];
        v += p[256+tid]; v += p[512+tid]; v += p[768+tid];
        float mu = blockSum256(v, rbuf) * (1.0f/256.0f);
        float d = v - mu;
        float var = blockSum256(d*d, rbuf) * (1.0f/256.0f);
        ws[OFF_XL + b*512 + 256 + tid] = d * rsqrtf(var + 1e-5f);
    }
    grid.sync();

    // Phase B: gemm512 — g -> (ot = g&15, bt = g>>4), verbatim k_gemm<512,256,0>
    {
        int ot = g & 15, bt = g >> 4;
        float acc[2][4];
        #pragma unroll
        for (int i=0;i<2;i++){
            #pragma unroll
            for (int j=0;j<4;j++) acc[i][j]=0.f;
        }
        gemm_pass<512>(ws + OFF_XL, Wih0, As, Wsh, acc, bt, ot, tid);
        gemm_pass<256>(ws + OFF_H,  Whh0, As, Wsh, acc, bt, ot, tid);
        #pragma unroll
        for (int i=0;i<2;i++){
            float4 v;
            v.x = acc[i][0]; v.y = acc[i][1]; v.z = acc[i][2]; v.w = acc[i][3];
            *(float4*)(ws + OFF_GB + (bt*32+ty*2+i)*1024 + ot*64 + tx*4) = v;
        }
    }
    grid.sync();

    // Phase C: layer-0 gates (verbatim k_gates l=0), b = 2g, 2g+1
    for (int bb = 0; bb < 2; bb++){
        int b = g*2 + bb;
        const float* gg_ = ws + OFF_GB + b*1024;
        float ig = gg_[tid], fg = gg_[256+tid], ggv = gg_[512+tid], og = gg_[768+tid];
        int idx = b*256 + tid;
        float cold = ws[OFF_C + idx];
        float cl = sigf(fg)*cold + sigf(ig)*tanhf(ggv);
        float hl = sigf(og)*tanhf(cl);
        ws[OFF_C + idx] = cl;
        ws[OFF_H + idx] = hl;
    }
    grid.sync();

    // Phase D: gemm256 — verbatim k_gemm<256,256,0>
    {
        int ot = g & 15, bt = g >> 4;
        float acc[2][4];
        #pragma unroll
        for (int i=0;i<2;i++){
            #pragma unroll
            for (int j=0;j<4;j++) acc[i][j]=0.f;
        }
        gemm_pass<256>(ws + OFF_H,          Wih1, As, Wsh, acc, bt, ot, tid);
        gemm_pass<256>(ws + OFF_H + BB*256, Whh1, As, Wsh, acc, bt, ot, tid);
        #pragma unroll
        for (int i=0;i<2;i++){
            float4 v;
            v.x = acc[i][0]; v.y = acc[i][1]; v.z = acc[i][2]; v.w = acc[i][3];
            *(float4*)(ws + OFF_GB + (bt*32+ty*2+i)*1024 + ot*64 + tx*4) = v;
        }
    }
    grid.sync();

    // Phase E: layer-1 gates + LN + relu -> rmn (verbatim k_mn), b = 2g, 2g+1
    for (int bb = 0; bb < 2; bb++){
        int b = g*2 + bb;
        const float* gg_ = ws + OFF_GB + b*1024;
        float ig = gg_[tid], fg = gg_[256+tid], ggv = gg_[512+tid], og = gg_[768+tid];
        int idx = BB*256 + b*256 + tid;
        float cold = ws[OFF_C + idx];
        float cl = sigf(fg)*cold + sigf(ig)*tanhf(ggv);
        float hl = sigf(og)*tanhf(cl);
        ws[OFF_C + idx] = cl;
        ws[OFF_H + idx] = hl;
        float mu = blockSum256(hl, rbuf) * (1.0f/256.0f);
        float d = hl - mu;
        float var = blockSum256(d*d, rbuf) * (1.0f/256.0f);
        ws[OFF_RMN + b*256 + tid] = fmaxf(d * rsqrtf(var + 1e-5f), 0.0f);
    }
    grid.sync();

    // Phase F: heads2 — g<32 -> (bx = g&7, bt = g>>3), verbatim k_heads2
    if (g < 32){
        int bx = g & 7, bt = g >> 3;
        int ot = bx & 3;
        const float* W = (bx < 4) ? Wm1 : Wv1;
        float* C = ws + ((bx < 4) ? OFF_TM : OFF_TV);
        float acc[2][4];
        #pragma unroll
        for (int i=0;i<2;i++){
            #pragma unroll
            for (int j=0;j<4;j++) acc[i][j]=0.f;
        }
        gemm_pass<256>(ws + OFF_RMN, W, As, Wsh, acc, bt, ot, tid);
        #pragma unroll
        for (int i=0;i<2;i++){
            float4 v;
            v.x = fmaxf(acc[i][0],0.f); v.y = fmaxf(acc[i][1],0.f);
            v.z = fmaxf(acc[i][2],0.f); v.w = fmaxf(acc[i][3],0.f);
            *(float4*)(C + (bt*32+ty*2+i)*256 + ot*64 + tx*4) = v;
        }
    }
    grid.sync();

    // Phase G: head (verbatim k_head), b = 2g, 2g+1
    for (int bb = 0; bb < 2; bb++){
        int b = g*2 + bb;
        int w = tid >> 6, lane = tid & 63;
        #pragma unroll
        for (int p = 0; p < 2; p++){
            int oi = p*4 + w;
            if (oi < 6){
                int j = (oi < 3) ? oi : oi - 3;
                const float* tb = ws + ((oi < 3) ? OFF_TM : OFF_TV) + b*256;
                const float* wr = ((oi < 3) ? Wm2 : Wv2) + j*256;
                float pa = 0.f;
                #pragma unroll
                for (int q = 0; q < 4; q++) pa += tb[lane + 64*q] * wr[lane + 64*q];
                for (int off = 32; off > 0; off >>= 1) pa += __shfl_down(pa, off, 64);
                if (lane == 0){
                    if (oi < 3){
                        float mv = tanhf(pa) * dlm[j] + ws[OFF_ANCHOR + b*3 + j];
                        out[((b*NSTEP + s)*5 + (t+1))*3 + j] = mv;
                        ws[OFF_ANCHOR + b*3 + j] = mv;
                    } else {
                        out[OUT_VAR + ((b*NSTEP + s)*5 + (t+1))*3 + j] = sigf(pa)*0.1f;
                    }
                }
            }
        }
    }
}

extern "C" void kernel_launch(void* const* d_in, const int* in_sizes, int n_in,
                              void* d_out, int out_size, void* d_ws, size_t ws_size,
                              hipStream_t stream)
{
    (void)in_sizes; (void)n_in; (void)out_size; (void)ws_size;
    const float* inp  = (const float*)d_in[0];
    const float* mp   = (const float*)d_in[1];
    const float* endp = (const float*)d_in[2];
    const float* dlm  = (const float*)d_in[3];
    const float* Wenc = (const float*)d_in[4];
    const float* Wq   = (const float*)d_in[5];
    const float* Wk   = (const float*)d_in[6];
    const float* Wv   = (const float*)d_in[7];
    const float* Win  = (const float*)d_in[8];
    const float* Wout = (const float*)d_in[9];
    const float* Wmap1= (const float*)d_in[10];
    const float* Wmap2= (const float*)d_in[11];
    const float* Wih0 = (const float*)d_in[12];
    const float* Wih1 = (const float*)d_in[13];
    const float* Whh0 = (const float*)d_in[14];
    const float* Whh1 = (const float*)d_in[15];
    const float* Wm1  = (const float*)d_in[16];
    const float* Wm2  = (const float*)d_in[17];
    const float* Wv1  = (const float*)d_in[18];
    const float* Wv2  = (const float*)d_in[19];
    float* out = (float*)d_out;
    float* ws  = (float*)d_ws;

    k_init<<<2, 256, 0, stream>>>(inp, ws);
    k_pre<<<NSTEP, 256, 0, stream>>>(Wq, Wk, Wv, Win, Wout, ws);
    for (int s = 0; s < NSTEP; s++){
        for (int t = 0; t < NITER; t++){
            k_mapenc<<<BB, MT, 0, stream>>>(mp, ws, out, Wenc, endp, s, t,
                                            (t == 0 && s > 0) ? 1 : 0);
            k_big<<<dim3(4, 4, BB), 256, 0, stream>>>(ws, Wmap1 + s*65536, Wmap2 + s*256, s);
            {
                const float* a_ih0 = Wih0 + s*524288;
                const float* a_hh0 = Whh0 + s*262144;
                const float* a_ih1 = Wih1 + s*262144;
                const float* a_hh1 = Whh1 + s*262144;
                const float* a_m1  = Wm1 + s*65536;
                const float* a_v1  = Wv1 + s*65536;
                const float* a_m2  = Wm2 + s*768;
                const float* a_v2  = Wv2 + s*768;
                const float* a_dlm = dlm;
                float* a_ws = ws;
                float* a_out = out;
                int sv = s, tv = t;
                void* args[13] = {(void*)&a_ih0, (void*)&a_hh0, (void*)&a_ih1, (void*)&a_hh1,
                                  (void*)&a_m1, (void*)&a_v1, (void*)&a_m2, (void*)&a_v2,
                                  (void*)&a_dlm, (void*)&a_ws, (void*)&a_out, (void*)&sv, (void*)&tv};
                hipLaunchCooperativeKernel((const void*)k_tail, dim3(64), dim3(256),
                                           args, 0, stream);
            }
        }
    }
    k_mapenc<<<BB, MT, 0, stream>>>(mp, ws, out, Wenc, endp, 3, 4, 0);
}

// Round 12
// 4036.983 us; speedup vs baseline: 1.2097x; 1.2097x over previous
//
#include <hip/hip_runtime.h>

#define BB 128
#define NPTS 20000
#define NSTEP 4
#define NITER 4
#define MT 1024

// ws float offsets
#define OFF_ANCHOR 0
#define OFF_G      384
#define OFF_AO     400
#define OFF_U      2448
#define OFF_XL     67984
#define OFF_H      166288     // h0; h1 at +BB*256
#define OFF_C      231824     // C0 parity-A; C1 at +BB*256 (in-place)
#define OFF_GB     297360     // k_big partials, then g0 gates (gemm512 out)
#define OFF_C0B    428432     // C0 parity-B
#define OFF_GB2    461200     // g1 gates (gemm256 out), 131072 floats

// d_out float offsets
#define OUT_VAR   7680
#define OUT_VIEWS 15360

__device__ __forceinline__ float sigf(float x){ return 1.0f/(1.0f+expf(-x)); }

__device__ __forceinline__ float blockSum256(float v, float* buf){
    for (int off = 32; off > 0; off >>= 1) v += __shfl_down(v, off, 64);
    int tid = threadIdx.x;
    __syncthreads();
    if ((tid & 63) == 0) buf[tid >> 6] = v;
    __syncthreads();
    return (buf[0] + buf[1]) + (buf[2] + buf[3]);
}

__device__ __forceinline__ float blockSum256g(float v, float* buf, int tid){
    for (int off = 32; off > 0; off >>= 1) v += __shfl_down(v, off, 64);
    __syncthreads();
    if (tid < 256 && (tid & 63) == 0) buf[tid >> 6] = v;
    __syncthreads();
    return (buf[0] + buf[1]) + (buf[2] + buf[3]);
}

__device__ __forceinline__ double blockSum256d(double v, double* buf){
    for (int off = 32; off > 0; off >>= 1) v += __shfl_down(v, off, 64);
    int tid = threadIdx.x;
    __syncthreads();
    if ((tid & 63) == 0) buf[tid >> 6] = v;
    __syncthreads();
    return (buf[0] + buf[1]) + (buf[2] + buf[3]);
}

// ---------------- init ----------------
__global__ __launch_bounds__(256) void k_init(const float* __restrict__ inp, float* __restrict__ ws)
{
    int i = blockIdx.x*256 + threadIdx.x;
    if (i < BB*3) ws[OFF_ANCHOR + i] = inp[i];
}

// Precompute per-step G (2x2) and Ao (256x2) with fp64 accumulation.
__global__ __launch_bounds__(256) void k_pre(const float* __restrict__ Wq, const float* __restrict__ Wk,
                                             const float* __restrict__ Wv, const float* __restrict__ Win,
                                             const float* __restrict__ Wout, float* __restrict__ ws)
{
    __shared__ float wql[512], wkl[512], wvl[512];
    __shared__ double avl[512];
    __shared__ double dbuf[4];
    int s = blockIdx.x, t = threadIdx.x;
    wql[t] = Wq[s*512 + t];   wql[256+t] = Wq[s*512 + 256 + t];
    wkl[t] = Wk[s*512 + t];   wkl[256+t] = Wk[s*512 + 256 + t];
    wvl[t] = Wv[s*512 + t];   wvl[256+t] = Wv[s*512 + 256 + t];
    __syncthreads();
    const float* wq = Win + s*196608 + t*256;
    const float* wk = wq + 65536;
    const float* wv = wq + 131072;
    double aq0=0,aq1=0,ak0=0,ak1=0,av0=0,av1=0;
    for (int j = 0; j < 256; j++){
        double a = wq[j], b = wk[j], c = wv[j];
        aq0 += a*(double)wql[j*2]; aq1 += a*(double)wql[j*2+1];
        ak0 += b*(double)wkl[j*2]; ak1 += b*(double)wkl[j*2+1];
        av0 += c*(double)wvl[j*2]; av1 += c*(double)wvl[j*2+1];
    }
    avl[t*2] = av0; avl[t*2+1] = av1;
    double g00 = blockSum256d(aq0*ak0, dbuf);
    double g01 = blockSum256d(aq0*ak1, dbuf);
    double g10 = blockSum256d(aq1*ak0, dbuf);
    double g11 = blockSum256d(aq1*ak1, dbuf);
    if (t == 0){
        ws[OFF_G + s*4+0] = (float)g00; ws[OFF_G + s*4+1] = (float)g01;
        ws[OFF_G + s*4+2] = (float)g10; ws[OFF_G + s*4+3] = (float)g11;
    }
    const float* wo = Wout + s*65536 + t*256;
    double o0 = 0.0, o1 = 0.0;
    for (int j = 0; j < 256; j++){
        double w = wo[j];
        o0 += w*avl[j*2]; o1 += w*avl[j*2+1];
    }
    ws[OFF_AO + s*512 + t*2]   = (float)o0;
    ws[OFF_AO + s*512 + t*2+1] = (float)o1;
}

// ---------------- fused: map top-256 + views + enc LN + attn -> U + step init (1024 thr) ----------------
__global__ __launch_bounds__(MT) void k_mapenc(const float* __restrict__ mp, float* __restrict__ ws,
                                               float* __restrict__ out, const float* __restrict__ Wenc,
                                               const float* __restrict__ endp, int s, int t, int wprev)
{
    __shared__ unsigned int histx[256], histy[256];
    __shared__ float vx[1024], vy[1024];
    __shared__ float candx[448], candy[448];
    __shared__ float mxS[256], myS[256];
    __shared__ int scanx[256], scany[256];
    __shared__ int shjx, shjy;
    __shared__ unsigned int cnt_in, cntx, cnty;
    __shared__ float rbuf[4];
    int tid = threadIdx.x, b = blockIdx.x;
    int lane = tid & 63;
    float ax = ws[OFF_ANCHOR + b*3 + 0];
    float ay = ws[OFF_ANCHOR + b*3 + 1];
    float th = ws[OFF_ANCHOR + b*3 + 2];
    float cth = cosf(th), sth = sinf(th);
    if (tid < 256){ histx[tid] = 0u; histy[tid] = 0u; }
    if (tid == 0){ cnt_in = 0u; cntx = 0u; cnty = 0u; }
    __syncthreads();
    for (int i = tid; i < NPTS; i += MT){
        float dx = mp[i] - ax, dy = mp[NPTS + i] - ay;
        float rx = cth*dx + sth*dy;
        float ry = cth*dy - sth*dx;
        float d  = sqrtf(rx*rx + ry*ry);
        bool keep = (d < 10.0f);
        unsigned long long mask = __ballot(keep);
        if (keep){
            unsigned long long lower = mask & ((1ull << lane) - 1ull);
            int leader = __ffsll((unsigned long long)mask) - 1;
            unsigned base = 0;
            if (lane == leader) base = atomicAdd(&cnt_in, (unsigned)__popcll(mask));
            base = __shfl(base, leader, 64);
            unsigned p = base + (unsigned)__popcll(lower);
            if (p < 1024u){ vx[p] = rx; vy[p] = ry; }
            int bx = min(max((int)((rx + 10.0f)*12.8f), 0), 255);
            int by = min(max((int)((ry + 10.0f)*12.8f), 0), 255);
            atomicAdd(&histx[bx], 1u); atomicAdd(&histy[by], 1u);
        }
    }
    __syncthreads();
    int total = (int)min(cnt_in, 1024u);
    int K = min(256, total);
    int px = 0, py = 0;
    if (tid < 256){
        px = (int)histx[tid]; py = (int)histy[tid];
        scanx[tid] = px; scany[tid] = py;
    }
    __syncthreads();
    for (int off = 1; off < 256; off <<= 1){
        int vxs = 0, vys = 0;
        if (tid < 256){
            vxs = (tid >= off) ? scanx[tid - off] : 0;
            vys = (tid >= off) ? scany[tid - off] : 0;
        }
        __syncthreads();
        if (tid < 256){ scanx[tid] += vxs; scany[tid] += vys; }
        __syncthreads();
    }
    if (K > 0){
        if (tid < 256){
            if (scanx[tid] - px < K && scanx[tid] >= K) shjx = tid;
            if (scany[tid] - py < K && scany[tid] >= K) shjy = tid;
        }
    } else if (tid == 0){ shjx = -1; shjy = -1; }
    __syncthreads();
    int jx = shjx, jy = shjy;
    for (int i = tid; i < total; i += MT){
        float vxa = vx[i], vya = vy[i];
        int bx = min(max((int)((vxa + 10.0f)*12.8f), 0), 255);
        int by = min(max((int)((vya + 10.0f)*12.8f), 0), 255);
        bool kx = (bx <= jx), ky = (by <= jy);
        unsigned long long mx_ = __ballot(kx);
        if (kx){
            unsigned long long lower = mx_ & ((1ull << lane) - 1ull);
            int leader = __ffsll((unsigned long long)mx_) - 1;
            unsigned base = 0;
            if (lane == leader) base = atomicAdd(&cntx, (unsigned)__popcll(mx_));
            base = __shfl(base, leader, 64);
            unsigned p = base + (unsigned)__popcll(lower);
            if (p < 448u) candx[p] = vxa;
        }
        unsigned long long my_ = __ballot(ky);
        if (ky){
            unsigned long long lower = my_ & ((1ull << lane) - 1ull);
            int leader = __ffsll((unsigned long long)my_) - 1;
            unsigned base = 0;
            if (lane == leader) base = atomicAdd(&cnty, (unsigned)__popcll(my_));
            base = __shfl(base, leader, 64);
            unsigned p = base + (unsigned)__popcll(lower);
            if (p < 448u) candy[p] = vya;
        }
    }
    __syncthreads();
    int cx = (int)min(cntx, 448u), cy = (int)min(cnty, 448u);
    // exact rank-select (ties by index; equal values interchange -> same output values)
    for (int i = tid; i < cx; i += MT){
        float v = candx[i];
        int r = 0;
        for (int j2 = 0; j2 < cx; j2++){
            float w2 = candx[j2];
            r += (w2 < v) || (w2 == v && j2 < i);
        }
        if (r < 256) mxS[r] = v;
    }
    for (int i = tid; i < cy; i += MT){
        float v = candy[i];
        int r = 0;
        for (int j2 = 0; j2 < cy; j2++){
            float w2 = candy[j2];
            r += (w2 < v) || (w2 == v && j2 < i);
        }
        if (r < 256) myS[r] = v;
    }
    __syncthreads();
    float mlx = 0.f, mly = 0.f;
    if (tid < 256){
        mlx = (tid < K) ? mxS[tid] : 0.0f;
        mly = (tid < K) ? myS[tid] : 0.0f;
        int obase = OUT_VIEWS + (((b*NSTEP + s)*5 + t)*2)*256;
        out[obase + tid]       = mlx;
        out[obase + 256 + tid] = mly;
        if (wprev){
            int pbase = OUT_VIEWS + (((b*NSTEP + (s-1))*5 + 4)*2)*256;
            out[pbase + tid]       = mlx;
            out[pbase + 256 + tid] = mly;
        }
    }
    if (t == 4) return;
    __syncthreads();
    if (tid < 256){ mxS[tid] = mlx; myS[tid] = mly; }   // zero-padded ml
    __syncthreads();
    // enc_a -> LN -> xl[0:256]
    float accv = 0.f, dd = 0.f;
    if (tid < 256){
        float a0 = ax, a1 = ay, a2 = th;
        float z9[9] = {a0, a1, a2, a0-endp[0], a1-endp[1], a2-endp[2], 0.01f, 0.01f, 0.01f};
        const float* w = Wenc + s*2304 + tid*9;
        #pragma unroll
        for (int j2 = 0; j2 < 9; j2++) accv += z9[j2]*w[j2];
    }
    float mu = blockSum256g(accv, rbuf, tid) * (1.0f/256.0f);
    dd = accv - mu;
    float var = blockSum256g(tid < 256 ? dd*dd : 0.f, rbuf, tid) * (1.0f/256.0f);
    if (tid < 256)
        ws[OFF_XL + b*512 + tid] = dd * rsqrtf(var + 1e-5f);
    // rank-2 attention -> u
    if (tid < 256){
        float g00 = ws[OFF_G + s*4+0], g01 = ws[OFF_G + s*4+1];
        float g10 = ws[OFF_G + s*4+2], g11 = ws[OFF_G + s*4+3];
        float xq = mxS[tid], yq = myS[tid];
        float t0 = g00*xq + g10*yq;
        float t1 = g01*xq + g11*yq;
        float mxv = -1e30f;
        for (int j2 = 0; j2 < 256; j2++){
            float l = (t0*mxS[j2] + t1*myS[j2]) * 0.0625f;
            mxv = fmaxf(mxv, l);
        }
        float sum = 0.f, ux = 0.f, uy = 0.f;
        for (int j2 = 0; j2 < 256; j2++){
            float l = (t0*mxS[j2] + t1*myS[j2]) * 0.0625f;
            float e = expf(l - mxv);
            sum += e; ux += e*mxS[j2]; uy += e*myS[j2];
        }
        float inv = 1.0f/sum;
        ws[OFF_U + b*512 + tid*2]   = ux*inv;
        ws[OFF_U + b*512 + tid*2+1] = uy*inv;
        if (t == 0){
            ws[OFF_H + b*256 + tid] = 1.0f;
            ws[OFF_H + BB*256 + b*256 + tid] = 1.0f;
            ws[OFF_C + b*256 + tid] = 1.0f;
            ws[OFF_C + BB*256 + b*256 + tid] = 1.0f;
            if (tid < 3){
                out[((b*NSTEP + s)*5 + 0)*3 + tid] = ws[OFF_ANCHOR + b*3 + tid];
                out[OUT_VAR + ((b*NSTEP + s)*5 + 0)*3 + tid] = 0.01f;
            }
        }
    }
}

// ---------------- k_big: round-10 verbatim (97us proven) -> GB partials ----------------
__global__ __launch_bounds__(256) void k_big(float* __restrict__ ws, const float* __restrict__ W1,
                                             const float* __restrict__ W2, int s)
{
    __shared__ __align__(16) float ul[512];
    __shared__ float aol[128];
    __shared__ float w2l[64];
    __shared__ __align__(16) float xt[64*36];
    __shared__ __align__(16) float w1t[64*36];
    __shared__ float red[64*17];
    int sct = blockIdx.x, st = blockIdx.y, b = blockIdx.z;
    int tid = threadIdx.x, tx = tid & 15, ty = tid >> 4;
    {
        float2 uv = *(const float2*)(ws + OFF_U + b*512 + tid*2);
        ul[tid*2] = uv.x; ul[tid*2+1] = uv.y;
        if (tid < 128) aol[tid] = ws[OFF_AO + s*512 + st*128 + tid];
        if (tid < 64)  w2l[tid] = W2[sct*64 + tid];
    }
    __syncthreads();
    float acc[4][4];
    #pragma unroll
    for (int i=0;i<4;i++){
        #pragma unroll
        for (int j=0;j<4;j++) acc[i][j] = 0.f;
    }
    for (int mt = 0; mt < 8; mt++){
        {
            int cl = tid >> 2, f0 = tid & 3;
            const float* g = W1 + (sct*64 + cl)*256 + mt*32 + f0*4;
            float4 v0 = *(const float4*)g;
            float4 v1 = *(const float4*)(g + 16);
            *(float4*)(w1t + cl*36 + f0*4)      = v0;
            *(float4*)(w1t + cl*36 + f0*4 + 16) = v1;
        }
        {
            int r = tid >> 2, mg = tid & 3;
            float A0 = aol[r*2], A1 = aol[r*2+1];
            int m0 = mt*32 + mg*4;
            float4 o0, o1;
            o0.x = fmaxf(A0*ul[(m0+0)*2] + A1*ul[(m0+0)*2+1], 0.f);
            o0.y = fmaxf(A0*ul[(m0+1)*2] + A1*ul[(m0+1)*2+1], 0.f);
            o0.z = fmaxf(A0*ul[(m0+2)*2] + A1*ul[(m0+2)*2+1], 0.f);
            o0.w = fmaxf(A0*ul[(m0+3)*2] + A1*ul[(m0+3)*2+1], 0.f);
            int m1 = mt*32 + (mg+4)*4;
            o1.x = fmaxf(A0*ul[(m1+0)*2] + A1*ul[(m1+0)*2+1], 0.f);
            o1.y = fmaxf(A0*ul[(m1+1)*2] + A1*ul[(m1+1)*2+1], 0.f);
            o1.z = fmaxf(A0*ul[(m1+2)*2] + A1*ul[(m1+2)*2+1], 0.f);
            o1.w = fmaxf(A0*ul[(m1+3)*2] + A1*ul[(m1+3)*2+1], 0.f);
            *(float4*)(xt + r*36 + mg*4)     = o0;
            *(float4*)(xt + r*36 + (mg+4)*4) = o1;
        }
        __syncthreads();
        #pragma unroll
        for (int m4 = 0; m4 < 8; m4++){
            float4 xv[4], wv[4];
            #pragma unroll
            for (int i=0;i<4;i++) xv[i] = *(const float4*)(xt + (ty + 16*i)*36 + m4*4);
            #pragma unroll
            for (int j=0;j<4;j++) wv[j] = *(const float4*)(w1t + (tx + 16*j)*36 + m4*4);
            #pragma unroll
            for (int i=0;i<4;i++){
                #pragma unroll
                for (int j=0;j<4;j++){
                    acc[i][j] += xv[i].x*wv[j].x + xv[i].y*wv[j].y + xv[i].z*wv[j].z + xv[i].w*wv[j].w;
                }
            }
        }
        __syncthreads();
    }
    #pragma unroll
    for (int i=0;i<4;i++){
        float p = 0.f;
        #pragma unroll
        for (int j=0;j<4;j++) p += fmaxf(acc[i][j], 0.f) * w2l[tx + 16*j];
        red[(ty + 16*i)*17 + tx] = p;
    }
    __syncthreads();
    if (tid < 64){
        float sm = 0.f;
        #pragma unroll
        for (int q=0;q<16;q++) sm += red[tid*17 + q];
        ws[OFF_GB + b*1024 + sct*256 + st*64 + tid] = sm;
    }
}

// sum 4 partials (sct ascending) -> LN -> xl[:,256:512]
__global__ __launch_bounds__(256) void k_lnencm(float* __restrict__ ws)
{
    __shared__ float rbuf[4];
    int b = blockIdx.x, t = threadIdx.x;
    const float* p = ws + OFF_GB + b*1024;
    float v = p[t];
    v += p[256+t]; v += p[512+t]; v += p[768+t];
    float mu = blockSum256(v, rbuf) * (1.0f/256.0f);
    float d = v - mu;
    float var = blockSum256(d*d, rbuf) * (1.0f/256.0f);
    ws[OFF_XL + b*512 + 256 + t] = d * rsqrtf(var + 1e-5f);
}

// ---------------- generic small GEMM pass (verbatim) ----------------
template<int K>
__device__ __forceinline__ void gemm_pass(const float* __restrict__ A, const float* __restrict__ W,
                                          float* As, float* Wsh, float (&acc)[2][4],
                                          int bt, int ot, int tid)
{
    int tx = tid & 15, ty = tid >> 4;
    for (int kt = 0; kt < K/32; kt++){
        {
            int bb = tid >> 3, kk = (tid & 7) * 4;
            float4 v = *(const float4*)(A + (bt*32+bb)*K + kt*32 + kk);
            float* ap = As + bb*33 + kk;
            ap[0]=v.x; ap[1]=v.y; ap[2]=v.z; ap[3]=v.w;
        }
        {
            int oo = tid >> 2, kk = (tid & 3) * 8;
            const float* g = W + (ot*64+oo)*K + kt*32 + kk;
            float4 v0 = *(const float4*)g;
            float4 v1 = *(const float4*)(g + 4);
            float* wp = Wsh + oo*33 + kk;
            wp[0]=v0.x; wp[1]=v0.y; wp[2]=v0.z; wp[3]=v0.w;
            wp[4]=v1.x; wp[5]=v1.y; wp[6]=v1.z; wp[7]=v1.w;
        }
        __syncthreads();
        #pragma unroll
        for (int kk = 0; kk < 32; kk++){
            float a0 = As[(ty*2)*33 + kk], a1 = As[(ty*2+1)*33 + kk];
            float w0 = Wsh[(tx*4)*33+kk],   w1 = Wsh[(tx*4+1)*33+kk];
            float w2 = Wsh[(tx*4+2)*33+kk], w3 = Wsh[(tx*4+3)*33+kk];
            acc[0][0] += a0*w0; acc[0][1] += a0*w1; acc[0][2] += a0*w2; acc[0][3] += a0*w3;
            acc[1][0] += a1*w0; acc[1][1] += a1*w1; acc[1][2] += a1*w2; acc[1][3] += a1*w3;
        }
        __syncthreads();
    }
}

template<int K>
__device__ __forceinline__ void stage_w(const float* __restrict__ W, float* Wsh, int ot, int kt, int tid)
{
    int oo = tid >> 2, kk = (tid & 3) * 8;
    const float* g = W + (ot*64+oo)*K + kt*32 + kk;
    float4 v0 = *(const float4*)g;
    float4 v1 = *(const float4*)(g + 4);
    float* wp = Wsh + oo*33 + kk;
    wp[0]=v0.x; wp[1]=v0.y; wp[2]=v0.z; wp[3]=v0.w;
    wp[4]=v1.x; wp[5]=v1.y; wp[6]=v1.z; wp[7]=v1.w;
}

template<int K1, int K2, int RELU>
__global__ __launch_bounds__(256) void k_gemm(const float* __restrict__ A1, const float* __restrict__ W1,
                                              const float* __restrict__ A2, const float* __restrict__ W2,
                                              float* __restrict__ C, int Osz)
{
    __shared__ float As[32*33];
    __shared__ float Wsh[64*33];
    int tid = threadIdx.x, tx = tid & 15, ty = tid >> 4;
    int ot = blockIdx.x, bt = blockIdx.y;
    float acc[2][4];
    #pragma unroll
    for (int i=0;i<2;i++){
        #pragma unroll
        for (int j=0;j<4;j++) acc[i][j]=0.f;
    }
    gemm_pass<K1>(A1, W1, As, Wsh, acc, bt, ot, tid);
    if constexpr (K2 > 0){
        gemm_pass<K2>(A2, W2, As, Wsh, acc, bt, ot, tid);
    }
    #pragma unroll
    for (int i=0;i<2;i++){
        float4 v;
        v.x = acc[i][0]; v.y = acc[i][1]; v.z = acc[i][2]; v.w = acc[i][3];
        if (RELU){ v.x=fmaxf(v.x,0.f); v.y=fmaxf(v.y,0.f); v.z=fmaxf(v.z,0.f); v.w=fmaxf(v.w,0.f); }
        *(float4*)(C + (bt*32+ty*2+i)*Osz + ot*64 + tx*4) = v;
    }
}

// ---------------- fused: gates0 (x16 redundant, ping-pong C0) + gemm256 -> GB2 ----------------
__global__ __launch_bounds__(256) void k_g256(const float* __restrict__ Wih1, const float* __restrict__ Whh1,
                                              float* __restrict__ ws, int t)
{
    __shared__ float h0t[32*257];
    __shared__ float As[32*33];
    __shared__ float Wsh[64*33];
    int tid = threadIdx.x, tx = tid & 15, ty = tid >> 4;
    int ot = blockIdx.x, bt = blockIdx.y;
    int crd = (t & 1) ? OFF_C0B : OFF_C;
    int cwr = (t & 1) ? OFF_C : OFF_C0B;
    // layer-0 gates (k_gates verbatim formulas); duplicate identical writes across ot-blocks
    for (int bb = 0; bb < 32; bb++){
        int b = bt*32 + bb;
        const float* g = ws + OFF_GB + b*1024;
        float ig = g[tid], fg = g[256+tid], gg = g[512+tid], og = g[768+tid];
        float cold = ws[crd + b*256 + tid];
        float cl = sigf(fg)*cold + sigf(ig)*tanhf(gg);
        float hl = sigf(og)*tanhf(cl);
        ws[cwr + b*256 + tid] = cl;
        ws[OFF_H + b*256 + tid] = hl;
        h0t[bb*257 + tid] = hl;
    }
    __syncthreads();
    float acc[2][4];
    #pragma unroll
    for (int i=0;i<2;i++){
        #pragma unroll
        for (int j=0;j<4;j++) acc[i][j]=0.f;
    }
    // pass1: h0 @ Wih1^T from LDS tile (same values, same k-ascending chain)
    for (int kt = 0; kt < 8; kt++){
        stage_w<256>(Wih1, Wsh, ot, kt, tid);
        __syncthreads();
        #pragma unroll
        for (int kk = 0; kk < 32; kk++){
            float a0 = h0t[(ty*2)*257 + kt*32 + kk], a1 = h0t[(ty*2+1)*257 + kt*32 + kk];
            float w0 = Wsh[(tx*4)*33+kk],   w1 = Wsh[(tx*4+1)*33+kk];
            float w2 = Wsh[(tx*4+2)*33+kk], w3 = Wsh[(tx*4+3)*33+kk];
            acc[0][0] += a0*w0; acc[0][1] += a0*w1; acc[0][2] += a0*w2; acc[0][3] += a0*w3;
            acc[1][0] += a1*w0; acc[1][1] += a1*w1; acc[1][2] += a1*w2; acc[1][3] += a1*w3;
        }
        __syncthreads();
    }
    // pass2: h1prev @ Whh1^T (verbatim)
    gemm_pass<256>(ws + OFF_H + BB*256, Whh1, As, Wsh, acc, bt, ot, tid);
    #pragma unroll
    for (int i=0;i<2;i++){
        float4 v;
        v.x = acc[i][0]; v.y = acc[i][1]; v.z = acc[i][2]; v.w = acc[i][3];
        *(float4*)(ws + OFF_GB2 + (bt*32+ty*2+i)*1024 + ot*64 + tx*4) = v;
    }
}

// ---------------- fused per-b: gates1 + LN + relu + heads GEMMs + head ----------------
__global__ __launch_bounds__(256) void k_tailb(const float* __restrict__ Wm1, const float* __restrict__ Wv1,
                                               const float* __restrict__ Wm2, const float* __restrict__ Wv2,
                                               const float* __restrict__ dlm, float* __restrict__ ws,
                                               float* __restrict__ out, int s, int t)
{
    __shared__ float rmn[256];
    __shared__ float tml[256], tvl[256];
    __shared__ float Wsh2[256*33];
    __shared__ float rbuf[4];
    int b = blockIdx.x, tid = threadIdx.x;
    // gates1 + LN + relu (k_mn verbatim; single writer per b, C1 in-place)
    {
        const float* g = ws + OFF_GB2 + b*1024;
        float ig = g[tid], fg = g[256+tid], gg = g[512+tid], og = g[768+tid];
        int idx = BB*256 + b*256 + tid;
        float cold = ws[OFF_C + idx];
        float cl = sigf(fg)*cold + sigf(ig)*tanhf(gg);
        float hl = sigf(og)*tanhf(cl);
        ws[OFF_C + idx] = cl;
        ws[OFF_H + idx] = hl;
        float mu = blockSum256(hl, rbuf) * (1.0f/256.0f);
        float d = hl - mu;
        float var = blockSum256(d*d, rbuf) * (1.0f/256.0f);
        rmn[tid] = fmaxf(d * rsqrtf(var + 1e-5f), 0.0f);
    }
    __syncthreads();
    // tm = relu(rmn . Wm1 rows), tv = relu(rmn . Wv1 rows); k ascending += chains (heads2-equivalent)
    float am = 0.f, av = 0.f;
    for (int pass = 0; pass < 2; pass++){
        const float* W = pass ? Wv1 : Wm1;
        float a = 0.f;
        for (int kt = 0; kt < 8; kt++){
            // stage 256x32 tile coalesced (stride-33 rows, scalar stores)
            {
                int o = (tid >> 3);
                int kk = (tid & 7)*4;
                #pragma unroll
                for (int r8 = 0; r8 < 8; r8++){
                    int oo = r8*32 + o;
                    float4 v = *(const float4*)(W + oo*256 + kt*32 + kk);
                    float* wp = Wsh2 + oo*33 + kk;
                    wp[0]=v.x; wp[1]=v.y; wp[2]=v.z; wp[3]=v.w;
                }
            }
            __syncthreads();
            #pragma unroll
            for (int kk = 0; kk < 32; kk++){
                a += rmn[kt*32 + kk] * Wsh2[tid*33 + kk];
            }
            __syncthreads();
        }
        if (pass == 0) am = a; else av = a;
    }
    tml[tid] = fmaxf(am, 0.f);
    tvl[tid] = fmaxf(av, 0.f);
    __syncthreads();
    // head (verbatim tree, tb from LDS)
    {
        int w = tid >> 6, lane = tid & 63;
        #pragma unroll
        for (int p = 0; p < 2; p++){
            int oi = p*4 + w;
            if (oi < 6){
                int j = (oi < 3) ? oi : oi - 3;
                const float* tb = (oi < 3) ? tml : tvl;
                const float* wr = ((oi < 3) ? Wm2 : Wv2) + j*256;
                float pa = 0.f;
                #pragma unroll
                for (int q = 0; q < 4; q++) pa += tb[lane + 64*q] * wr[lane + 64*q];
                for (int off = 32; off > 0; off >>= 1) pa += __shfl_down(pa, off, 64);
                if (lane == 0){
                    if (oi < 3){
                        float mv = tanhf(pa) * dlm[j] + ws[OFF_ANCHOR + b*3 + j];
                        out[((b*NSTEP + s)*5 + (t+1))*3 + j] = mv;
                        ws[OFF_ANCHOR + b*3 + j] = mv;
                    } else {
                        out[OUT_VAR + ((b*NSTEP + s)*5 + (t+1))*3 + j] = sigf(pa)*0.1f;
                    }
                }
            }
        }
    }
}

extern "C" void kernel_launch(void* const* d_in, const int* in_sizes, int n_in,
                              void* d_out, int out_size, void* d_ws, size_t ws_size,
                              hipStream_t stream)
{
    (void)in_sizes; (void)n_in; (void)out_size; (void)ws_size;
    const float* inp  = (const float*)d_in[0];
    const float* mp   = (const float*)d_in[1];
    const float* endp = (const float*)d_in[2];
    const float* dlm  = (const float*)d_in[3];
    const float* Wenc = (const float*)d_in[4];
    const float* Wq   = (const float*)d_in[5];
    const float* Wk   = (const float*)d_in[6];
    const float* Wv   = (const float*)d_in[7];
    const float* Win  = (const float*)d_in[8];
    const float* Wout = (const float*)d_in[9];
    const float* Wmap1= (const float*)d_in[10];
    const float* Wmap2= (const float*)d_in[11];
    const float* Wih0 = (const float*)d_in[12];
    const float* Wih1 = (const float*)d_in[13];
    const float* Whh0 = (const float*)d_in[14];
    const float* Whh1 = (const float*)d_in[15];
    const float* Wm1  = (const float*)d_in[16];
    const float* Wm2  = (const float*)d_in[17];
    const float* Wv1  = (const float*)d_in[18];
    const float* Wv2  = (const float*)d_in[19];
    float* out = (float*)d_out;
    float* ws  = (float*)d_ws;

    k_init<<<2, 256, 0, stream>>>(inp, ws);
    k_pre<<<NSTEP, 256, 0, stream>>>(Wq, Wk, Wv, Win, Wout, ws);
    for (int s = 0; s < NSTEP; s++){
        for (int t = 0; t < NITER; t++){
            k_mapenc<<<BB, MT, 0, stream>>>(mp, ws, out, Wenc, endp, s, t,
                                            (t == 0 && s > 0) ? 1 : 0);
            k_big<<<dim3(4, 4, BB), 256, 0, stream>>>(ws, Wmap1 + s*65536, Wmap2 + s*256, s);
            k_lnencm<<<BB, 256, 0, stream>>>(ws);
            k_gemm<512,256,0><<<dim3(16,4), 256, 0, stream>>>(ws+OFF_XL, Wih0 + s*524288,
                                                              ws+OFF_H,  Whh0 + s*262144,
                                                              ws+OFF_GB, 1024);
            k_g256<<<dim3(16,4), 256, 0, stream>>>(Wih1 + s*262144, Whh1 + s*262144, ws, t);
            k_tailb<<<BB, 256, 0, stream>>>(Wm1 + s*65536, Wv1 + s*65536,
                                            Wm2 + s*768, Wv2 + s*768, dlm, ws, out, s, t);
        }
    }
    k_mapenc<<<BB, MT, 0, stream>>>(mp, ws, out, Wenc, endp, 3, 4, 0);
}

// Round 13
// 3741.103 us; speedup vs baseline: 1.3053x; 1.0791x over previous
//
#include <hip/hip_runtime.h>

#define BB 128
#define NPTS 20000
#define NSTEP 4
#define NITER 4
#define MT 1024

// ws float offsets (round-2 proven layout)
#define OFF_ANCHOR 0
#define OFF_G      384
#define OFF_AO     400
#define OFF_U      2448
#define OFF_XL     67984
#define OFF_H      166288
#define OFF_C      231824
#define OFF_GB     297360
#define OFF_RMN    428432
#define OFF_TM     461200
#define OFF_TV     493968

// d_out float offsets
#define OUT_VAR   7680
#define OUT_VIEWS 15360

__device__ __forceinline__ float sigf(float x){ return 1.0f/(1.0f+expf(-x)); }

__device__ __forceinline__ float blockSum256(float v, float* buf){
    for (int off = 32; off > 0; off >>= 1) v += __shfl_down(v, off, 64);
    int tid = threadIdx.x;
    __syncthreads();
    if ((tid & 63) == 0) buf[tid >> 6] = v;
    __syncthreads();
    return (buf[0] + buf[1]) + (buf[2] + buf[3]);
}

// same reduction tree, valid for blocks >256 threads: only waves 0-3 write partials
__device__ __forceinline__ float blockSum256g(float v, float* buf, int tid){
    for (int off = 32; off > 0; off >>= 1) v += __shfl_down(v, off, 64);
    __syncthreads();
    if (tid < 256 && (tid & 63) == 0) buf[tid >> 6] = v;
    __syncthreads();
    return (buf[0] + buf[1]) + (buf[2] + buf[3]);
}

__device__ __forceinline__ double blockSum256d(double v, double* buf){
    for (int off = 32; off > 0; off >>= 1) v += __shfl_down(v, off, 64);
    int tid = threadIdx.x;
    __syncthreads();
    if ((tid & 63) == 0) buf[tid >> 6] = v;
    __syncthreads();
    return (buf[0] + buf[1]) + (buf[2] + buf[3]);
}

// ---------------- init ----------------
__global__ __launch_bounds__(256) void k_init(const float* __restrict__ inp, float* __restrict__ ws)
{
    int i = blockIdx.x*256 + threadIdx.x;
    if (i < BB*3) ws[OFF_ANCHOR + i] = inp[i];
}

// Precompute per-step G (2x2) and Ao (256x2) with fp64 accumulation.
__global__ __launch_bounds__(256) void k_pre(const float* __restrict__ Wq, const float* __restrict__ Wk,
                                             const float* __restrict__ Wv, const float* __restrict__ Win,
                                             const float* __restrict__ Wout, float* __restrict__ ws)
{
    __shared__ float wql[512], wkl[512], wvl[512];
    __shared__ double avl[512];
    __shared__ double dbuf[4];
    int s = blockIdx.x, t = threadIdx.x;
    wql[t] = Wq[s*512 + t];   wql[256+t] = Wq[s*512 + 256 + t];
    wkl[t] = Wk[s*512 + t];   wkl[256+t] = Wk[s*512 + 256 + t];
    wvl[t] = Wv[s*512 + t];   wvl[256+t] = Wv[s*512 + 256 + t];
    __syncthreads();
    const float* wq = Win + s*196608 + t*256;
    const float* wk = wq + 65536;
    const float* wv = wq + 131072;
    double aq0=0,aq1=0,ak0=0,ak1=0,av0=0,av1=0;
    for (int j = 0; j < 256; j++){
        double a = wq[j], b = wk[j], c = wv[j];
        aq0 += a*(double)wql[j*2]; aq1 += a*(double)wql[j*2+1];
        ak0 += b*(double)wkl[j*2]; ak1 += b*(double)wkl[j*2+1];
        av0 += c*(double)wvl[j*2]; av1 += c*(double)wvl[j*2+1];
    }
    avl[t*2] = av0; avl[t*2+1] = av1;
    double g00 = blockSum256d(aq0*ak0, dbuf);
    double g01 = blockSum256d(aq0*ak1, dbuf);
    double g10 = blockSum256d(aq1*ak0, dbuf);
    double g11 = blockSum256d(aq1*ak1, dbuf);
    if (t == 0){
        ws[OFF_G + s*4+0] = (float)g00; ws[OFF_G + s*4+1] = (float)g01;
        ws[OFF_G + s*4+2] = (float)g10; ws[OFF_G + s*4+3] = (float)g11;
    }
    const float* wo = Wout + s*65536 + t*256;
    double o0 = 0.0, o1 = 0.0;
    for (int j = 0; j < 256; j++){
        double w = wo[j];
        o0 += w*avl[j*2]; o1 += w*avl[j*2+1];
    }
    ws[OFF_AO + s*512 + t*2]   = (float)o0;
    ws[OFF_AO + s*512 + t*2+1] = (float)o1;
}

// ---------------- fused: map top-256 + views + enc LN + attn -> U + step init (1024 thr) ----------------
__global__ __launch_bounds__(MT) void k_mapenc(const float* __restrict__ mp, float* __restrict__ ws,
                                               float* __restrict__ out, const float* __restrict__ Wenc,
                                               const float* __restrict__ endp, int s, int t, int wprev)
{
    __shared__ unsigned int histx[256], histy[256];
    __shared__ float vx[1024], vy[1024];
    __shared__ float candx[448], candy[448];
    __shared__ float mxS[256], myS[256];
    __shared__ int scanx[256], scany[256];
    __shared__ int shjx, shjy;
    __shared__ unsigned int cnt_in, cntx, cnty;
    __shared__ float rbuf[4];
    int tid = threadIdx.x, b = blockIdx.x;
    float ax = ws[OFF_ANCHOR + b*3 + 0];
    float ay = ws[OFF_ANCHOR + b*3 + 1];
    float th = ws[OFF_ANCHOR + b*3 + 2];
    float cth = cosf(th), sth = sinf(th);
    if (tid < 256){ histx[tid] = 0u; histy[tid] = 0u; }
    if (tid == 0){ cnt_in = 0u; cntx = 0u; cnty = 0u; }
    __syncthreads();
    for (int i = tid; i < NPTS; i += MT){
        float dx = mp[i] - ax, dy = mp[NPTS + i] - ay;
        float rx = cth*dx + sth*dy;
        float ry = cth*dy - sth*dx;
        float d  = sqrtf(rx*rx + ry*ry);
        if (d < 10.0f){
            unsigned p = atomicAdd(&cnt_in, 1u);
            if (p < 1024u){ vx[p] = rx; vy[p] = ry; }
            int bx = min(max((int)((rx + 10.0f)*12.8f), 0), 255);
            int by = min(max((int)((ry + 10.0f)*12.8f), 0), 255);
            atomicAdd(&histx[bx], 1u); atomicAdd(&histy[by], 1u);
        }
    }
    __syncthreads();
    int total = (int)min(cnt_in, 1024u);
    int K = min(256, total);
    int px = 0, py = 0;
    if (tid < 256){
        px = (int)histx[tid]; py = (int)histy[tid];
        scanx[tid] = px; scany[tid] = py;
    }
    __syncthreads();
    for (int off = 1; off < 256; off <<= 1){
        int vxs = 0, vys = 0;
        if (tid < 256){
            vxs = (tid >= off) ? scanx[tid - off] : 0;
            vys = (tid >= off) ? scany[tid - off] : 0;
        }
        __syncthreads();
        if (tid < 256){ scanx[tid] += vxs; scany[tid] += vys; }
        __syncthreads();
    }
    if (K > 0){
        if (tid < 256){
            if (scanx[tid] - px < K && scanx[tid] >= K) shjx = tid;
            if (scany[tid] - py < K && scany[tid] >= K) shjy = tid;
        }
    } else if (tid == 0){ shjx = -1; shjy = -1; }
    __syncthreads();
    int jx = shjx, jy = shjy;
    for (int i = tid; i < total; i += MT){
        float v = vx[i];
        int bx = min(max((int)((v + 10.0f)*12.8f), 0), 255);
        if (bx <= jx){ unsigned p = atomicAdd(&cntx, 1u); if (p < 448u) candx[p] = v; }
        v = vy[i];
        int by = min(max((int)((v + 10.0f)*12.8f), 0), 255);
        if (by <= jy){ unsigned p = atomicAdd(&cnty, 1u); if (p < 448u) candy[p] = v; }
    }
    __syncthreads();
    int cx = (int)min(cntx, 448u), cy = (int)min(cnty, 448u);
    // exact rank-select (ties by index; equal values interchange -> same output values)
    for (int i = tid; i < cx; i += MT){
        float v = candx[i];
        int r = 0;
        for (int j2 = 0; j2 < cx; j2++){
            float w2 = candx[j2];
            r += (w2 < v) || (w2 == v && j2 < i);
        }
        if (r < 256) mxS[r] = v;
    }
    for (int i = tid; i < cy; i += MT){
        float v = candy[i];
        int r = 0;
        for (int j2 = 0; j2 < cy; j2++){
            float w2 = candy[j2];
            r += (w2 < v) || (w2 == v && j2 < i);
        }
        if (r < 256) myS[r] = v;
    }
    __syncthreads();
    float mlx = 0.f, mly = 0.f;
    if (tid < 256){
        mlx = (tid < K) ? mxS[tid] : 0.0f;
        mly = (tid < K) ? myS[tid] : 0.0f;
        int obase = OUT_VIEWS + (((b*NSTEP + s)*5 + t)*2)*256;
        out[obase + tid]       = mlx;
        out[obase + 256 + tid] = mly;
        if (wprev){
            int pbase = OUT_VIEWS + (((b*NSTEP + (s-1))*5 + 4)*2)*256;
            out[pbase + tid]       = mlx;
            out[pbase + 256 + tid] = mly;
        }
    }
    if (t == 4) return;
    __syncthreads();
    if (tid < 256){ mxS[tid] = mlx; myS[tid] = mly; }   // zero-padded ml
    __syncthreads();
    // enc_a -> LN -> xl[0:256]
    float accv = 0.f, dd = 0.f;
    if (tid < 256){
        float a0 = ax, a1 = ay, a2 = th;
        float z9[9] = {a0, a1, a2, a0-endp[0], a1-endp[1], a2-endp[2], 0.01f, 0.01f, 0.01f};
        const float* w = Wenc + s*2304 + tid*9;
        #pragma unroll
        for (int j2 = 0; j2 < 9; j2++) accv += z9[j2]*w[j2];
    }
    float mu = blockSum256g(accv, rbuf, tid) * (1.0f/256.0f);
    dd = accv - mu;
    float var = blockSum256g(tid < 256 ? dd*dd : 0.f, rbuf, tid) * (1.0f/256.0f);
    if (tid < 256)
        ws[OFF_XL + b*512 + tid] = dd * rsqrtf(var + 1e-5f);
    // rank-2 attention -> u
    if (tid < 256){
        float g00 = ws[OFF_G + s*4+0], g01 = ws[OFF_G + s*4+1];
        float g10 = ws[OFF_G + s*4+2], g11 = ws[OFF_G + s*4+3];
        float xq = mxS[tid], yq = myS[tid];
        float t0 = g00*xq + g10*yq;
        float t1 = g01*xq + g11*yq;
        float mxv = -1e30f;
        for (int j2 = 0; j2 < 256; j2++){
            float l = (t0*mxS[j2] + t1*myS[j2]) * 0.0625f;
            mxv = fmaxf(mxv, l);
        }
        float sum = 0.f, ux = 0.f, uy = 0.f;
        for (int j2 = 0; j2 < 256; j2++){
            float l = (t0*mxS[j2] + t1*myS[j2]) * 0.0625f;
            float e = expf(l - mxv);
            sum += e; ux += e*mxS[j2]; uy += e*myS[j2];
        }
        float inv = 1.0f/sum;
        ws[OFF_U + b*512 + tid*2]   = ux*inv;
        ws[OFF_U + b*512 + tid*2+1] = uy*inv;
        if (t == 0){
            ws[OFF_H + b*256 + tid] = 1.0f;
            ws[OFF_H + BB*256 + b*256 + tid] = 1.0f;
            ws[OFF_C + b*256 + tid] = 1.0f;
            ws[OFF_C + BB*256 + b*256 + tid] = 1.0f;
            if (tid < 3){
                out[((b*NSTEP + s)*5 + 0)*3 + tid] = ws[OFF_ANCHOR + b*3 + tid];
                out[OUT_VAR + ((b*NSTEP + s)*5 + 0)*3 + tid] = 0.01f;
            }
        }
    }
}

// ---------------- k_big: round-2 chains, broadcast xv row map (ty+16i) ----------------
__global__ __launch_bounds__(256) void k_big(float* __restrict__ ws, const float* __restrict__ W1,
                                             const float* __restrict__ W2, int s)
{
    __shared__ __align__(16) float ul[512];
    __shared__ float aol[128];
    __shared__ float w2l[64];
    __shared__ __align__(16) float xt[64*36];
    __shared__ __align__(16) float w1t[64*36];
    __shared__ float red[64*17];
    int sct = blockIdx.x, st = blockIdx.y, b = blockIdx.z;
    int tid = threadIdx.x, tx = tid & 15, ty = tid >> 4;
    {
        float2 uv = *(const float2*)(ws + OFF_U + b*512 + tid*2);
        ul[tid*2] = uv.x; ul[tid*2+1] = uv.y;
        if (tid < 128) aol[tid] = ws[OFF_AO + s*512 + st*128 + tid];
        if (tid < 64)  w2l[tid] = W2[sct*64 + tid];
    }
    __syncthreads();
    float acc[4][4];
    #pragma unroll
    for (int i=0;i<4;i++){
        #pragma unroll
        for (int j=0;j<4;j++) acc[i][j] = 0.f;
    }
    for (int mt = 0; mt < 8; mt++){
        {
            int cl = tid >> 2, f0 = tid & 3;
            const float* g = W1 + (sct*64 + cl)*256 + mt*32 + f0*4;
            float4 v0 = *(const float4*)g;
            float4 v1 = *(const float4*)(g + 16);
            *(float4*)(w1t + cl*36 + f0*4)      = v0;
            *(float4*)(w1t + cl*36 + f0*4 + 16) = v1;
        }
        {
            int r = tid >> 2, mg = tid & 3;
            float A0 = aol[r*2], A1 = aol[r*2+1];
            int m0 = mt*32 + mg*4;
            float4 o0, o1;
            o0.x = fmaxf(A0*ul[(m0+0)*2] + A1*ul[(m0+0)*2+1], 0.f);
            o0.y = fmaxf(A0*ul[(m0+1)*2] + A1*ul[(m0+1)*2+1], 0.f);
            o0.z = fmaxf(A0*ul[(m0+2)*2] + A1*ul[(m0+2)*2+1], 0.f);
            o0.w = fmaxf(A0*ul[(m0+3)*2] + A1*ul[(m0+3)*2+1], 0.f);
            int m1 = mt*32 + (mg+4)*4;
            o1.x = fmaxf(A0*ul[(m1+0)*2] + A1*ul[(m1+0)*2+1], 0.f);
            o1.y = fmaxf(A0*ul[(m1+1)*2] + A1*ul[(m1+1)*2+1], 0.f);
            o1.z = fmaxf(A0*ul[(m1+2)*2] + A1*ul[(m1+2)*2+1], 0.f);
            o1.w = fmaxf(A0*ul[(m1+3)*2] + A1*ul[(m1+3)*2+1], 0.f);
            *(float4*)(xt + r*36 + mg*4)     = o0;
            *(float4*)(xt + r*36 + (mg+4)*4) = o1;
        }
        __syncthreads();
        #pragma unroll
        for (int m4 = 0; m4 < 8; m4++){
            float4 xv[4], wv[4];
            #pragma unroll
            for (int i=0;i<4;i++) xv[i] = *(const float4*)(xt + (ty + 16*i)*36 + m4*4);
            #pragma unroll
            for (int j=0;j<4;j++) wv[j] = *(const float4*)(w1t + (tx + 16*j)*36 + m4*4);
            #pragma unroll
            for (int i=0;i<4;i++){
                #pragma unroll
                for (int j=0;j<4;j++){
                    acc[i][j] += xv[i].x*wv[j].x + xv[i].y*wv[j].y + xv[i].z*wv[j].z + xv[i].w*wv[j].w;
                }
            }
        }
        __syncthreads();
    }
    #pragma unroll
    for (int i=0;i<4;i++){
        float p = 0.f;
        #pragma unroll
        for (int j=0;j<4;j++) p += fmaxf(acc[i][j], 0.f) * w2l[tx + 16*j];
        red[(ty + 16*i)*17 + tx] = p;
    }
    __syncthreads();
    if (tid < 64){
        float sm = 0.f;
        #pragma unroll
        for (int q=0;q<16;q++) sm += red[tid*17 + q];
        ws[OFF_GB + b*1024 + sct*256 + st*64 + tid] = sm;
    }
}

// sum 4 partials (sct ascending) -> LN -> xl[:,256:512]
__global__ __launch_bounds__(256) void k_lnencm(float* __restrict__ ws)
{
    __shared__ float rbuf[4];
    int b = blockIdx.x, t = threadIdx.x;
    const float* p = ws + OFF_GB + b*1024;
    float v = p[t];
    v += p[256+t]; v += p[512+t]; v += p[768+t];
    float mu = blockSum256(v, rbuf) * (1.0f/256.0f);
    float d = v - mu;
    float var = blockSum256(d*d, rbuf) * (1.0f/256.0f);
    ws[OFF_XL + b*512 + 256 + t] = d * rsqrtf(var + 1e-5f);
}

// ---------------- generic small GEMM ----------------
template<int K>
__device__ __forceinline__ void gemm_pass(const float* __restrict__ A, const float* __restrict__ W,
                                          float* As, float* Wsh, float (&acc)[2][4],
                                          int bt, int ot, int tid)
{
    int tx = tid & 15, ty = tid >> 4;
    for (int kt = 0; kt < K/32; kt++){
        {
            int bb = tid >> 3, kk = (tid & 7) * 4;
            float4 v = *(const float4*)(A + (bt*32+bb)*K + kt*32 + kk);
            float* ap = As + bb*33 + kk;
            ap[0]=v.x; ap[1]=v.y; ap[2]=v.z; ap[3]=v.w;
        }
        {
            int oo = tid >> 2, kk = (tid & 3) * 8;
            const float* g = W + (ot*64+oo)*K + kt*32 + kk;
            float4 v0 = *(const float4*)g;
            float4 v1 = *(const float4*)(g + 4);
            float* wp = Wsh + oo*33 + kk;
            wp[0]=v0.x; wp[1]=v0.y; wp[2]=v0.z; wp[3]=v0.w;
            wp[4]=v1.x; wp[5]=v1.y; wp[6]=v1.z; wp[7]=v1.w;
        }
        __syncthreads();
        #pragma unroll
        for (int kk = 0; kk < 32; kk++){
            float a0 = As[(ty*2)*33 + kk], a1 = As[(ty*2+1)*33 + kk];
            float w0 = Wsh[(tx*4)*33+kk],   w1 = Wsh[(tx*4+1)*33+kk];
            float w2 = Wsh[(tx*4+2)*33+kk], w3 = Wsh[(tx*4+3)*33+kk];
            acc[0][0] += a0*w0; acc[0][1] += a0*w1; acc[0][2] += a0*w2; acc[0][3] += a0*w3;
            acc[1][0] += a1*w0; acc[1][1] += a1*w1; acc[1][2] += a1*w2; acc[1][3] += a1*w3;
        }
        __syncthreads();
    }
}

template<int K1, int K2, int RELU>
__global__ __launch_bounds__(256) void k_gemm(const float* __restrict__ A1, const float* __restrict__ W1,
                                              const float* __restrict__ A2, const float* __restrict__ W2,
                                              float* __restrict__ C, int Osz)
{
    __shared__ float As[32*33];
    __shared__ float Wsh[64*33];
    int tid = threadIdx.x, tx = tid & 15, ty = tid >> 4;
    int ot = blockIdx.x, bt = blockIdx.y;
    float acc[2][4];
    #pragma unroll
    for (int i=0;i<2;i++){
        #pragma unroll
        for (int j=0;j<4;j++) acc[i][j]=0.f;
    }
    gemm_pass<K1>(A1, W1, As, Wsh, acc, bt, ot, tid);
    if constexpr (K2 > 0){
        gemm_pass<K2>(A2, W2, As, Wsh, acc, bt, ot, tid);
    }
    #pragma unroll
    for (int i=0;i<2;i++){
        float4 v;
        v.x = acc[i][0]; v.y = acc[i][1]; v.z = acc[i][2]; v.w = acc[i][3];
        if (RELU){ v.x=fmaxf(v.x,0.f); v.y=fmaxf(v.y,0.f); v.z=fmaxf(v.z,0.f); v.w=fmaxf(v.w,0.f); }
        *(float4*)(C + (bt*32+ty*2+i)*Osz + ot*64 + tx*4) = v;
    }
}

// fused two head GEMMs
__global__ __launch_bounds__(256) void k_heads2(const float* __restrict__ A, const float* __restrict__ Wm1,
                                                const float* __restrict__ Wv1, float* __restrict__ ws)
{
    __shared__ float As[32*33];
    __shared__ float Wsh[64*33];
    int tid = threadIdx.x, tx = tid & 15, ty = tid >> 4;
    int bx = blockIdx.x, bt = blockIdx.y;
    int ot = bx & 3;
    const float* W = (bx < 4) ? Wm1 : Wv1;
    float* C = ws + ((bx < 4) ? OFF_TM : OFF_TV);
    float acc[2][4];
    #pragma unroll
    for (int i=0;i<2;i++){
        #pragma unroll
        for (int j=0;j<4;j++) acc[i][j]=0.f;
    }
    gemm_pass<256>(A, W, As, Wsh, acc, bt, ot, tid);
    #pragma unroll
    for (int i=0;i<2;i++){
        float4 v;
        v.x = fmaxf(acc[i][0],0.f); v.y = fmaxf(acc[i][1],0.f);
        v.z = fmaxf(acc[i][2],0.f); v.w = fmaxf(acc[i][3],0.f);
        *(float4*)(C + (bt*32+ty*2+i)*256 + ot*64 + tx*4) = v;
    }
}

// LSTM layer-0 gates
__global__ __launch_bounds__(256) void k_gates(float* __restrict__ ws, int l)
{
    int b = blockIdx.x, t = threadIdx.x;
    const float* g = ws + OFF_GB + b*1024;
    float ig = g[t], fg = g[256+t], gg = g[512+t], og = g[768+t];
    int idx = l*BB*256 + b*256 + t;
    float cold = ws[OFF_C + idx];
    float cl = sigf(fg)*cold + sigf(ig)*tanhf(gg);
    float hl = sigf(og)*tanhf(cl);
    ws[OFF_C + idx] = cl;
    ws[OFF_H + idx] = hl;
}

// fused: layer-1 gates + LN(h1) + relu -> rmn
__global__ __launch_bounds__(256) void k_mn(float* __restrict__ ws)
{
    __shared__ float rbuf[4];
    int b = blockIdx.x, t = threadIdx.x;
    const float* g = ws + OFF_GB + b*1024;
    float ig = g[t], fg = g[256+t], gg = g[512+t], og = g[768+t];
    int idx = BB*256 + b*256 + t;
    float cold = ws[OFF_C + idx];
    float cl = sigf(fg)*cold + sigf(ig)*tanhf(gg);
    float hl = sigf(og)*tanhf(cl);
    ws[OFF_C + idx] = cl;
    ws[OFF_H + idx] = hl;
    float mu = blockSum256(hl, rbuf) * (1.0f/256.0f);
    float d = hl - mu;
    float var = blockSum256(d*d, rbuf) * (1.0f/256.0f);
    ws[OFF_RMN + b*256 + t] = fmaxf(d * rsqrtf(var + 1e-5f), 0.0f);
}

// heads: mean/var 3-vec; updates anchor, writes outputs
__global__ __launch_bounds__(256) void k_head(const float* __restrict__ Wm2, const float* __restrict__ Wv2,
                                              const float* __restrict__ dlm, float* __restrict__ ws,
                                              float* __restrict__ out, int s, int t)
{
    int b = blockIdx.x, tid = threadIdx.x;
    int w = tid >> 6, lane = tid & 63;
    #pragma unroll
    for (int p = 0; p < 2; p++){
        int oi = p*4 + w;
        if (oi < 6){
            int j = (oi < 3) ? oi : oi - 3;
            const float* tb = ws + ((oi < 3) ? OFF_TM : OFF_TV) + b*256;
            const float* wr = ((oi < 3) ? Wm2 : Wv2) + j*256;
            float pa = 0.f;
            #pragma unroll
            for (int q = 0; q < 4; q++) pa += tb[lane + 64*q] * wr[lane + 64*q];
            for (int off = 32; off > 0; off >>= 1) pa += __shfl_down(pa, off, 64);
            if (lane == 0){
                if (oi < 3){
                    float mv = tanhf(pa) * dlm[j] + ws[OFF_ANCHOR + b*3 + j];
                    out[((b*NSTEP + s)*5 + (t+1))*3 + j] = mv;
                    ws[OFF_ANCHOR + b*3 + j] = mv;
                } else {
                    out[OUT_VAR + ((b*NSTEP + s)*5 + (t+1))*3 + j] = sigf(pa)*0.1f;
                }
            }
        }
    }
}

extern "C" void kernel_launch(void* const* d_in, const int* in_sizes, int n_in,
                              void* d_out, int out_size, void* d_ws, size_t ws_size,
                              hipStream_t stream)
{
    (void)in_sizes; (void)n_in; (void)out_size; (void)ws_size;
    const float* inp  = (const float*)d_in[0];
    const float* mp   = (const float*)d_in[1];
    const float* endp = (const float*)d_in[2];
    const float* dlm  = (const float*)d_in[3];
    const float* Wenc = (const float*)d_in[4];
    const float* Wq   = (const float*)d_in[5];
    const float* Wk   = (const float*)d_in[6];
    const float* Wv   = (const float*)d_in[7];
    const float* Win  = (const float*)d_in[8];
    const float* Wout = (const float*)d_in[9];
    const float* Wmap1= (const float*)d_in[10];
    const float* Wmap2= (const float*)d_in[11];
    const float* Wih0 = (const float*)d_in[12];
    const float* Wih1 = (const float*)d_in[13];
    const float* Whh0 = (const float*)d_in[14];
    const float* Whh1 = (const float*)d_in[15];
    const float* Wm1  = (const float*)d_in[16];
    const float* Wm2  = (const float*)d_in[17];
    const float* Wv1  = (const float*)d_in[18];
    const float* Wv2  = (const float*)d_in[19];
    float* out = (float*)d_out;
    float* ws  = (float*)d_ws;

    k_init<<<2, 256, 0, stream>>>(inp, ws);
    k_pre<<<NSTEP, 256, 0, stream>>>(Wq, Wk, Wv, Win, Wout, ws);
    for (int s = 0; s < NSTEP; s++){
        for (int t = 0; t < NITER; t++){
            k_mapenc<<<BB, MT, 0, stream>>>(mp, ws, out, Wenc, endp, s, t,
                                            (t == 0 && s > 0) ? 1 : 0);
            k_big<<<dim3(4, 4, BB), 256, 0, stream>>>(ws, Wmap1 + s*65536, Wmap2 + s*256, s);
            k_lnencm<<<BB, 256, 0, stream>>>(ws);
            k_gemm<512,256,0><<<dim3(16,4), 256, 0, stream>>>(ws+OFF_XL, Wih0 + s*524288,
                                                              ws+OFF_H,  Whh0 + s*262144,
                                                              ws+OFF_GB, 1024);
            k_gates<<<BB, 256, 0, stream>>>(ws, 0);
            k_gemm<256,256,0><<<dim3(16,4), 256, 0, stream>>>(ws+OFF_H,          Wih1 + s*262144,
                                                              ws+OFF_H + BB*256, Whh1 + s*262144,
                                                              ws+OFF_GB, 1024);
            k_mn<<<BB, 256, 0, stream>>>(ws);
            k_heads2<<<dim3(8,4), 256, 0, stream>>>(ws+OFF_RMN, Wm1 + s*65536, Wv1 + s*65536, ws);
            k_head<<<BB, 256, 0, stream>>>(Wm2 + s*768, Wv2 + s*768, dlm, ws, out, s, t);
        }
    }
    k_mapenc<<<BB, MT, 0, stream>>>(mp, ws, out, Wenc, endp, 3, 4, 0);
}